// Round 3
// baseline (76.020 us; speedup 1.0000x reference)
//
#include <hip/hip_runtime.h>
#include <hip/hip_bf16.h>

// B=64, N=64, P=128, K=16, M=N*N=4096, T=4096
// Outputs: Z [64,64] (4096 f32) then w [64,128,4096] (33554432 f32), concatenated.
//
// Pipeline:
//   k_prep   : W2T[t][k] = W[k][t]^2            (into wout-scratch)
//   k_gemm   : part[tc][k][m] = sum_{t in chunk tc} W2T[t][k]*G[t][m]  (wout-scratch)
//   k_reduce : wg[k][m] = sum_tc part; E = exp(-wg)                    (into ws)
//   k_w_out  : w[b,p,:] = wg[idx(b,p)][:]       (overwrites wout incl. scratch)
//   k_z      : Z[b][i]  = sum_k E[k][i,:] . s[b,k,:]

// ---------------------------------------------------------------------------
__global__ __launch_bounds__(256) void k_prep(const float* __restrict__ W,
                                              float* __restrict__ W2T) {
    const int t = blockIdx.x * 256 + threadIdx.x;   // 16 blocks
    float v[16];
#pragma unroll
    for (int k = 0; k < 16; ++k) {
        float w = W[k * 4096 + t];                  // coalesced per k
        v[k] = w * w;
    }
    float4* dst = (float4*)(W2T + (size_t)t * 16);  // 64B contiguous per thread
#pragma unroll
    for (int q = 0; q < 4; ++q)
        dst[q] = make_float4(v[4*q], v[4*q+1], v[4*q+2], v[4*q+3]);
}

// ---------------------------------------------------------------------------
// grid 256 = 64 t-chunks x 4 m-groups. Thread owns one float4 of m, all 16 k.
// W2T[t] is wave-uniform -> scalar loads; G reads are 1KB/wave coalesced.
__global__ __launch_bounds__(256) void k_gemm(const float* __restrict__ G,
                                              const float* __restrict__ W2T,
                                              float* __restrict__ part) {
    const int mg  = blockIdx.x & 3;
    const int tc  = blockIdx.x >> 2;
    const int tid = threadIdx.x;
    const int mq  = mg * 256 + tid;                 // float4 column index (0..1023)
    const float4* G4 = (const float4*)G;

    float4 acc[16];
#pragma unroll
    for (int k = 0; k < 16; ++k) acc[k] = make_float4(0.f, 0.f, 0.f, 0.f);

    const int t0 = tc * 64;
    for (int t = t0; t < t0 + 64; ++t) {
        const float4 g4 = G4[(size_t)t * 1024 + mq];
        const float* w2 = W2T + (size_t)t * 16;     // uniform -> s_load
#pragma unroll
        for (int k = 0; k < 16; ++k) {
            const float s = w2[k];
            acc[k].x = fmaf(s, g4.x, acc[k].x);
            acc[k].y = fmaf(s, g4.y, acc[k].y);
            acc[k].z = fmaf(s, g4.z, acc[k].z);
            acc[k].w = fmaf(s, g4.w, acc[k].w);
        }
    }
    float4* pout = (float4*)part;
#pragma unroll
    for (int k = 0; k < 16; ++k)
        pout[(size_t)(tc * 16 + k) * 1024 + mq] = acc[k];
}

// ---------------------------------------------------------------------------
// gid = k*4096+m; part[tc*65536 + gid] summed over tc. 256 blocks.
__global__ __launch_bounds__(256) void k_reduce(const float* __restrict__ part,
                                                float* __restrict__ wg,
                                                float* __restrict__ E) {
    const int gid = blockIdx.x * 256 + threadIdx.x;
    float s = 0.f;
#pragma unroll 8
    for (int tc = 0; tc < 64; ++tc)
        s += part[(size_t)tc * 65536 + gid];
    wg[gid] = s;
    E[gid]  = expf(-s);
}

// ---------------------------------------------------------------------------
__global__ __launch_bounds__(256) void k_w_out(const float* __restrict__ xmask,
                                               const float* __restrict__ wg,
                                               float* __restrict__ wout) {
    const int bp  = blockIdx.x;       // 0..8191
    const int tid = threadIdx.x;
    const float* xm = xmask + (size_t)bp * 16;
    int k = 0;
#pragma unroll
    for (int i = 0; i < 16; ++i) k = (xm[i] > 0.5f) ? i : k;
    const float4* src = (const float4*)(wg + (size_t)k * 4096);
    float4*       dst = (float4*)(wout + (size_t)bp * 4096);
#pragma unroll
    for (int c = 0; c < 4; ++c)
        dst[c * 256 + tid] = src[c * 256 + tid];
}

// ---------------------------------------------------------------------------
// grid 256 = b(64) x iq(4). Block recomputes s[k][j] for its b (cheap, LDS),
// then does the 16-i x 16-k slice of the matvec.
__global__ __launch_bounds__(256) void k_z(const float* __restrict__ x,
                                           const float* __restrict__ xmask,
                                           const float* __restrict__ E,
                                           float* __restrict__ zout) {
    __shared__ float xs[8192];        // x[b] flat as [128][64]
    __shared__ float sw[4][16][64];   // per-wave private s accumulators
    __shared__ int   idx[128];
    __shared__ float zr[16][16];      // [k][i_local]
    const int b   = blockIdx.x >> 2;
    const int iq  = blockIdx.x & 3;
    const int tid = threadIdx.x;
    const int wv  = tid >> 6;
    const int ln  = tid & 63;

    const float4* xsrc = (const float4*)(x + (size_t)b * 8192);
#pragma unroll
    for (int c = 0; c < 8; ++c)
        ((float4*)xs)[c * 256 + tid] = xsrc[c * 256 + tid];

    if (tid < 128) {
        const float* xm = xmask + ((size_t)b * 128 + tid) * 16;
        int k = 0;
#pragma unroll
        for (int i = 0; i < 16; ++i) k = (xm[i] > 0.5f) ? i : k;
        idx[tid] = k;
    }
#pragma unroll
    for (int c = 0; c < 16; ++c)
        ((float*)sw)[c * 256 + tid] = 0.f;
    __syncthreads();

    for (int p = wv * 32; p < wv * 32 + 32; ++p) {
        int k = idx[p];
        sw[wv][k][ln] += xs[p * 64 + ln];
    }
    __syncthreads();

    for (int e = tid; e < 1024; e += 256) {
        int k2 = e >> 6, j = e & 63;
        sw[0][k2][j] = sw[0][k2][j] + sw[1][k2][j] + sw[2][k2][j] + sw[3][k2][j];
    }
    __syncthreads();

    {
        const int k  = tid >> 4;
        const int il = tid & 15;
        const int i  = iq * 16 + il;
        float a = 0.f;
        const float4* Er = (const float4*)(E + (size_t)k * 4096 + i * 64);
        const float4* sr = (const float4*)(&sw[0][k][0]);
#pragma unroll
        for (int j4 = 0; j4 < 16; ++j4) {
            float4 e4 = Er[j4];
            float4 s4 = sr[j4];
            a = fmaf(e4.x, s4.x, a);
            a = fmaf(e4.y, s4.y, a);
            a = fmaf(e4.z, s4.z, a);
            a = fmaf(e4.w, s4.w, a);
        }
        zr[k][il] = a;
    }
    __syncthreads();
    if (tid < 16) {
        float s = 0.f;
#pragma unroll
        for (int k = 0; k < 16; ++k) s += zr[k][tid];
        zout[b * 64 + iq * 16 + tid] = s;
    }
}

extern "C" void kernel_launch(void* const* d_in, const int* in_sizes, int n_in,
                              void* d_out, int out_size, void* d_ws, size_t ws_size,
                              hipStream_t stream) {
    const float* x     = (const float*)d_in[0];   // [64,64,128]
    const float* xmask = (const float*)d_in[1];   // [64,128,16]
    const float* W     = (const float*)d_in[2];   // [16,4096]
    const float* G     = (const float*)d_in[3];   // [4096,4096]

    float* zout = (float*)d_out;                  // [64,64]
    float* wout = (float*)d_out + 4096;           // [64,128,4096]

    // ws: wg [64K f32] + E [64K f32] = 512 KB
    float* wg = (float*)d_ws;
    float* E  = wg + 65536;

    // dead scratch inside the w-output region (overwritten by k_w_out):
    float* part = wout;                           // 64*16*4096 = 4M f32 (16 MB)
    float* W2T  = wout + 4194304;                 // 4096*16 f32 (256 KB)

    k_prep  <<<16,   256, 0, stream>>>(W, W2T);
    k_gemm  <<<256,  256, 0, stream>>>(G, W2T, part);
    k_reduce<<<256,  256, 0, stream>>>(part, wg, E);
    k_w_out <<<8192, 256, 0, stream>>>(xmask, wg, wout);
    k_z     <<<256,  256, 0, stream>>>(x, xmask, E, zout);
}

// Round 4
// 54.412 us; speedup vs baseline: 1.3971x; 1.3971x over previous
//
#include <hip/hip_runtime.h>
#include <hip/hip_bf16.h>

// B=64, N=64, P=128, K=16, M=N*N=4096, T=4096
// Outputs: Z [64,64] then w [64,128,4096], concatenated f32.
//
// Pipeline (3 kernels):
//   k_gemm   : part[tc][k][m] = sum_{t in 256-chunk} W[k][t]^2 * G[t][m]
//              (W^2 staged in LDS; in-block reduction over 16 t-sublanes)
//   k_reduce : wg = sum_tc part ; E = exp(-wg)
//   k_wz     : blocks 0..8191   -> w[b,p,:] = wg[idx(b,p)][:]
//              blocks 8192..8447 -> Z[b][i] = sum_k E[k][i,:] . s[b,k,:]

// ---------------------------------------------------------------------------
__global__ __launch_bounds__(256) void k_gemm(const float* __restrict__ W,
                                              const float* __restrict__ G,
                                              float* __restrict__ part) {
    __shared__ float  w2[16][256];     // 16 KB [k][t_local]
    __shared__ float4 red[8 * 256];    // 32 KB reduction staging
    const int tc  = blockIdx.x & 15;   // t-chunk (256 t each)
    const int mg  = blockIdx.x >> 4;   // m-slice (64 floats = 16 float4 each)
    const int tid = threadIdx.x;
    const int tt  = tid >> 4;          // 0..15 t-sublane
    const int col = tid & 15;          // 0..15 float4 within m-slice
    const int t0  = tc * 256;

    // stage W^2 for this t-chunk (coalesced per k)
#pragma unroll
    for (int k = 0; k < 16; ++k) {
        float v = W[k * 4096 + t0 + tid];
        w2[k][tid] = v * v;
    }
    __syncthreads();

    const float4* G4 = (const float4*)G;
    const int mq = mg * 16 + col;      // float4 column (0..1023)

    float4 acc[16];
#pragma unroll
    for (int k = 0; k < 16; ++k) acc[k] = make_float4(0.f, 0.f, 0.f, 0.f);

#pragma unroll 8
    for (int i = 0; i < 16; ++i) {
        const int tl = tt * 16 + i;
        const float4 g4 = G4[(size_t)(t0 + tl) * 1024 + mq];
#pragma unroll
        for (int k = 0; k < 16; ++k) {
            const float s = w2[k][tl];
            acc[k].x = fmaf(s, g4.x, acc[k].x);
            acc[k].y = fmaf(s, g4.y, acc[k].y);
            acc[k].z = fmaf(s, g4.z, acc[k].z);
            acc[k].w = fmaf(s, g4.w, acc[k].w);
        }
    }

    // in-block reduction over tt (two rounds of 8 k to bound LDS at 32 KB)
    float4* p4 = (float4*)part;
#pragma unroll
    for (int r = 0; r < 2; ++r) {
#pragma unroll
        for (int ks = 0; ks < 8; ++ks)
            red[ks * 256 + tid] = acc[r * 8 + ks];
        __syncthreads();
        if (tid < 128) {
            const int ks = tid >> 4;   // 0..7
            const int c2 = tid & 15;   // 0..15
            float4 s = make_float4(0.f, 0.f, 0.f, 0.f);
#pragma unroll
            for (int t2 = 0; t2 < 16; ++t2) {
                float4 v = red[ks * 256 + t2 * 16 + c2];
                s.x += v.x; s.y += v.y; s.z += v.z; s.w += v.w;
            }
            const int k = r * 8 + ks;
            p4[(size_t)tc * 16384 + (size_t)k * 1024 + mg * 16 + c2] = s;
        }
        __syncthreads();
    }
}

// ---------------------------------------------------------------------------
// grid 64 x 256: thread owns one float4 of wg/E, sums 16 tc partials.
__global__ __launch_bounds__(256) void k_reduce(const float* __restrict__ part,
                                                float* __restrict__ wg,
                                                float* __restrict__ E) {
    const int q = blockIdx.x * 256 + threadIdx.x;    // f4 id 0..16383
    const float4* p4 = (const float4*)part;
    float4 s = make_float4(0.f, 0.f, 0.f, 0.f);
#pragma unroll
    for (int tc = 0; tc < 16; ++tc) {
        float4 v = p4[(size_t)tc * 16384 + q];
        s.x += v.x; s.y += v.y; s.z += v.z; s.w += v.w;
    }
    ((float4*)wg)[q] = s;
    ((float4*)E)[q] = make_float4(expf(-s.x), expf(-s.y), expf(-s.z), expf(-s.w));
}

// ---------------------------------------------------------------------------
// blocks 0..8191: w gather.  blocks 8192..8447: Z (b = zb>>2, iq = zb&3).
__global__ __launch_bounds__(256) void k_wz(const float* __restrict__ x,
                                            const float* __restrict__ xmask,
                                            const float* __restrict__ wg,
                                            const float* __restrict__ E,
                                            float* __restrict__ wout,
                                            float* __restrict__ zout) {
    __shared__ float sw[4][16][64];   // 16 KB (z only)
    __shared__ int   idx[128];
    __shared__ float zr[16][16];
    const int tid = threadIdx.x;

    if (blockIdx.x < 8192) {
        const int bp = blockIdx.x;
        const float* xm = xmask + (size_t)bp * 16;
        int k = 0;
#pragma unroll
        for (int i = 0; i < 16; ++i) k = (xm[i] > 0.5f) ? i : k;
        const float4* src = (const float4*)(wg + (size_t)k * 4096);
        float4*       dst = (float4*)(wout + (size_t)bp * 4096);
#pragma unroll
        for (int c = 0; c < 4; ++c)
            dst[c * 256 + tid] = src[c * 256 + tid];
        return;
    }

    const int zb = blockIdx.x - 8192;
    const int b  = zb >> 2;
    const int iq = zb & 3;
    const int wv = tid >> 6;
    const int ln = tid & 63;

    if (tid < 128) {
        const float* xm = xmask + ((size_t)b * 128 + tid) * 16;
        int k = 0;
#pragma unroll
        for (int i = 0; i < 16; ++i) k = (xm[i] > 0.5f) ? i : k;
        idx[tid] = k;
    }
#pragma unroll
    for (int c = 0; c < 16; ++c)
        ((float*)sw)[c * 256 + tid] = 0.f;
    __syncthreads();

    // wave wv owns p in [wv*32, wv*32+32); lane = j; x read direct (L2-hot).
    const float* xb = x + (size_t)b * 8192;
    for (int p = wv * 32; p < wv * 32 + 32; ++p) {
        int k = idx[p];
        sw[wv][k][ln] += xb[p * 64 + ln];
    }
    __syncthreads();

    for (int e = tid; e < 1024; e += 256) {
        int k2 = e >> 6, j = e & 63;
        sw[0][k2][j] = sw[0][k2][j] + sw[1][k2][j] + sw[2][k2][j] + sw[3][k2][j];
    }
    __syncthreads();

    {
        const int k  = tid >> 4;
        const int il = tid & 15;
        const int i  = iq * 16 + il;
        float a = 0.f;
        const float4* Er = (const float4*)(E + (size_t)k * 4096 + i * 64);
        const float4* sr = (const float4*)(&sw[0][k][0]);
#pragma unroll
        for (int j4 = 0; j4 < 16; ++j4) {
            float4 e4 = Er[j4];
            float4 s4 = sr[j4];
            a = fmaf(e4.x, s4.x, a);
            a = fmaf(e4.y, s4.y, a);
            a = fmaf(e4.z, s4.z, a);
            a = fmaf(e4.w, s4.w, a);
        }
        zr[k][il] = a;
    }
    __syncthreads();
    if (tid < 16) {
        float s = 0.f;
#pragma unroll
        for (int k = 0; k < 16; ++k) s += zr[k][tid];
        zout[b * 64 + iq * 16 + tid] = s;
    }
}

extern "C" void kernel_launch(void* const* d_in, const int* in_sizes, int n_in,
                              void* d_out, int out_size, void* d_ws, size_t ws_size,
                              hipStream_t stream) {
    const float* x     = (const float*)d_in[0];   // [64,64,128]
    const float* xmask = (const float*)d_in[1];   // [64,128,16]
    const float* W     = (const float*)d_in[2];   // [16,4096]
    const float* G     = (const float*)d_in[3];   // [4096,4096]

    float* zout = (float*)d_out;                  // [64,64]
    float* wout = (float*)d_out + 4096;           // [64,128,4096]

    float* wg = (float*)d_ws;                     // 64K f32
    float* E  = wg + 65536;                       // 64K f32

    // partials live in the (dead-until-overwritten) w output region: 4 MB
    float* part = wout;                           // 16 tc * 16 k * 4096 m f32

    k_gemm  <<<1024, 256, 0, stream>>>(W, G, part);
    k_reduce<<<64,   256, 0, stream>>>(part, wg, E);
    k_wz    <<<8448, 256, 0, stream>>>(x, xmask, wg, E, wout, zout);
}